// Round 11
// baseline (16598.712 us; speedup 1.0000x reference)
//
#include <hip/hip_runtime.h>
#include <cstdint>
#include <cstddef>

#define HID   64
#define G3    192
#define LSEQ  4096
#define NCLS  230
#define TCH   64              // chunk length (steps per staged chunk)
#define NCH   (LSEQ / TCH)    // 64 chunks

using u16 = unsigned short;
using u32 = unsigned int;

__device__ __forceinline__ float bf2f(u16 u) {
    return __uint_as_float(((u32)u) << 16);
}
__device__ __forceinline__ u16 f2bf(float f) {
    u32 x = __float_as_uint(f);
    x += 0x7fffu + ((x >> 16) & 1u);
    return (u16)(x >> 16);
}
__device__ __forceinline__ void unpack2(u32 v, float& lo, float& hi) {
    lo = __uint_as_float(v << 16);
    hi = __uint_as_float(v & 0xffff0000u);
}

// 64-MAC dot of f32 weights (registers) against 64 bf16 values in LDS.
// r10 BUG (absmax 0.12): loop bound was i<4 = 32 elements. 64 bf16 = 8 uint4.
__device__ __forceinline__ float dot64(const float* wv, const u16* xr) {
    float a0 = 0.f, a1 = 0.f, a2 = 0.f, a3 = 0.f;
    const uint4* x4 = (const uint4*)xr;
    #pragma unroll
    for (int i = 0; i < 8; ++i) {
        uint4 q = x4[i];
        float f0,f1,f2,f3,f4,f5,f6,f7;
        unpack2(q.x, f0, f1); unpack2(q.y, f2, f3);
        unpack2(q.z, f4, f5); unpack2(q.w, f6, f7);
        a0 = fmaf(wv[8*i+0], f0, a0); a1 = fmaf(wv[8*i+1], f1, a1);
        a2 = fmaf(wv[8*i+2], f2, a2); a3 = fmaf(wv[8*i+3], f3, a3);
        a0 = fmaf(wv[8*i+4], f4, a0); a1 = fmaf(wv[8*i+5], f5, a1);
        a2 = fmaf(wv[8*i+6], f6, a2); a3 = fmaf(wv[8*i+7], f7, a3);
    }
    return (a0 + a1) + (a2 + a3);
}

// ---------------------------------------------------------------------------
// Chunked producer/consumer GRU layer. One block per (batch, dir); 576 thr:
//   role 0 (tid   0-191): scan — hidden matvec; lanes 0-63 also do gates.
//   role 1 (tid 192-383): input-proj partial K=[64:128) for chunk k+1.
//   role 2 (tid 384-575): input-proj partial K=[0:64) + bias + p1s -> gxb.
// All global I/O happens at chunk boundaries (stage X chunk in, flush h
// chunk out); steady-state steps are LDS-only, so the vmcnt(0) drain that
// __syncthreads emits (r9: ~900cy HBM latency in EVERY step) is amortized
// to once per 64 steps. gxb is double-buffered: scan consumes chunk k while
// producers build chunk k+1 between the same barriers.
// MODE 0: layer 0 (scalar f32 input); 1: middle; 2: last (lastb only).
// ---------------------------------------------------------------------------
template<int MODE>
__global__ __launch_bounds__(576, 1) void rec_cb(
    const void* __restrict__ xin,   // MODE0: [Bc][L] f32; else [Bc][L][128] bf16
    const float* __restrict__ wih,  // MODE0: [2][192]; else [2][192][128] f32
    const float* __restrict__ bih,  // [2][192] f32 (this layer)
    const float* __restrict__ whh,  // [2][192][64] f32 (this layer)
    const float* __restrict__ bhh,  // [2][192] f32 (this layer)
    u16* __restrict__ lout,         // [Bc][L][128] bf16 (MODE<=1)
    float* __restrict__ lastb,      // [B][128] f32 (MODE==2; aliases d_out)
    int bbase)
{
    const int bc  = blockIdx.x >> 1;
    const int d   = blockIdx.x & 1;
    const int tid = threadIdx.x;
    const int role = tid / G3;      // 0,1,2 — wave-uniform
    const int g    = tid % G3;

    __shared__ float gxb[2][TCH][G3];                    // 96 KiB
    __shared__ __align__(16) u16 xstage[TCH][128];       // 16 KiB
    __shared__ float p1s[G3];
    __shared__ float phs[G3];
    __shared__ float hs[HID];
    __shared__ __align__(16) u16 loutb[TCH][HID];        // 8 KiB

    float wv[64];
    float w0 = 0.f, bi = 0.f, bh = 0.f;

    if (role == 0) {
        const float4* p = (const float4*)(whh + (size_t)(d * G3 + g) * HID);
        #pragma unroll
        for (int i = 0; i < 16; ++i) {
            float4 v = p[i];
            wv[4*i] = v.x; wv[4*i+1] = v.y; wv[4*i+2] = v.z; wv[4*i+3] = v.w;
        }
        bh = bhh[d * G3 + g];
    } else if (role == 1) {
        if (MODE >= 1) {
            const float4* p = (const float4*)(wih + (size_t)(d * G3 + g) * 128 + 64);
            #pragma unroll
            for (int i = 0; i < 16; ++i) {
                float4 v = p[i];
                wv[4*i] = v.x; wv[4*i+1] = v.y; wv[4*i+2] = v.z; wv[4*i+3] = v.w;
            }
        }
    } else {
        if (MODE >= 1) {
            const float4* p = (const float4*)(wih + (size_t)(d * G3 + g) * 128);
            #pragma unroll
            for (int i = 0; i < 16; ++i) {
                float4 v = p[i];
                wv[4*i] = v.x; wv[4*i+1] = v.y; wv[4*i+2] = v.z; wv[4*i+3] = v.w;
            }
        } else {
            w0 = wih[d * G3 + g];
        }
        bi = bih[d * G3 + g];
    }

    if (tid < HID) hs[tid] = 0.f;

    const u16*   xb  = (const u16*)xin + (size_t)bc * LSEQ * 128;
    const float* xp  = (const float*)xin + (size_t)bc * LSEQ;
    float*       xs0 = (float*)&xstage[0][0];    // MODE0 alias (64 f32)

    auto prow = [&](int s) -> int { return d ? (LSEQ - 1 - s) : s; };

    // ---- stage X chunk 0 ----
    if (MODE == 0) {
        if (tid < TCH) xs0[tid] = xp[prow(tid)];
    } else if (tid < 128) {
        #pragma unroll
        for (int it = 0; it < 8; ++it) {
            int idx = it * 128 + tid;           // 0..1023 (16B units)
            int row = idx >> 4, seg = idx & 15;
            uint4 v = *(const uint4*)(xb + (size_t)prow(row) * 128 + seg * 8);
            *(uint4*)&xstage[row][seg * 8] = v;
        }
    }
    __syncthreads();

    // ---- prologue: produce gxb[0] from X chunk 0 ----
    if (MODE == 0) {
        if (role == 2) {
            for (int tt = 0; tt < TCH; ++tt)
                gxb[0][tt][g] = fmaf(w0, xs0[tt], bi);
        }
        __syncthreads();
    } else {
        for (int tt = 0; tt < TCH; ++tt) {
            if (role == 1) p1s[g] = dot64(wv, &xstage[tt][64]);
            __syncthreads();
            if (role == 2) gxb[0][tt][g] = dot64(wv, &xstage[tt][0]) + p1s[g] + bi;
            __syncthreads();
        }
    }

    // ---- main loop over chunks ----
    for (int k = 0; k < NCH; ++k) {
        const int knext = k + 1;
        const int kb = k & 1, knb = knext & 1;

        // boundary: flush lout chunk k-1; stage X chunk k+1
        if (MODE <= 1 && k > 0) {
            const int base_prev = (k - 1) * TCH;
            if (tid < 512) {
                #pragma unroll
                for (int rr = 0; rr < 4; ++rr) {
                    int idx = tid + rr * 512;          // u32 units, 0..2047
                    int row = idx >> 5, col = idx & 31;
                    u32 v = ((const u32*)loutb)[idx];
                    ((u32*)(lout + ((size_t)bc * LSEQ + prow(base_prev + row)) * 128 + d * HID))[col] = v;
                }
            }
        }
        if (knext < NCH && !(MODE == 2 && d == 1)) {
            if (MODE == 0) {
                if (tid < TCH) xs0[tid] = xp[prow(knext * TCH + tid)];
            } else if (tid < 128) {
                const int basen = knext * TCH;
                #pragma unroll
                for (int it = 0; it < 8; ++it) {
                    int idx = it * 128 + tid;
                    int row = idx >> 4, seg = idx & 15;
                    uint4 v = *(const uint4*)(xb + (size_t)prow(basen + row) * 128 + seg * 8);
                    *(uint4*)&xstage[row][seg * 8] = v;
                }
            }
        }
        __syncthreads();

        for (int tt = 0; tt < TCH; ++tt) {
            // ---- phase A: hidden matvec (scan) ∥ K-hi partial (prod1) ----
            if (role == 0) {
                float a0=0.f, a1=0.f, a2=0.f, a3=0.f;
                const float4* h4 = (const float4*)hs;
                #pragma unroll
                for (int i = 0; i < 16; ++i) {
                    float4 hv = h4[i];
                    a0 = fmaf(wv[4*i+0], hv.x, a0);
                    a1 = fmaf(wv[4*i+1], hv.y, a1);
                    a2 = fmaf(wv[4*i+2], hv.z, a2);
                    a3 = fmaf(wv[4*i+3], hv.w, a3);
                }
                phs[g] = (a0 + a1) + (a2 + a3) + bh;
            } else if (role == 1 && MODE >= 1 && knext < NCH) {
                p1s[g] = dot64(wv, &xstage[tt][64]);
            }
            __syncthreads();

            // ---- phase B: gates+h (lanes 0-63) ∥ gx finalize (prod2) ----
            if (tid < HID) {
                const int j = tid;
                const float* gx = gxb[kb][tt];
                const float r = 1.f / (1.f + __expf(-(gx[j]      + phs[j])));
                const float z = 1.f / (1.f + __expf(-(gx[64 + j] + phs[64 + j])));
                float y = fmaf(r, phs[128 + j], gx[128 + j]);
                y = fminf(fmaxf(y, -15.f), 15.f);
                const float e = __expf(-2.f * y);
                const float n = (1.f - e) / (1.f + e);       // tanh(y)
                const float hn = fmaf(z, hs[j] - n, n);      // (1-z)*n + z*h
                hs[j] = hn;
                if (MODE <= 1) {
                    loutb[tt][j] = f2bf(hn);
                } else {
                    if ((d == 0 && k == NCH - 1 && tt == TCH - 1) ||
                        (d == 1 && k == 0 && tt == 0))
                        lastb[(size_t)(bbase + bc) * 128 + d * HID + j] = hn;
                }
            } else if (role == 2 && knext < NCH) {
                float gxv;
                if (MODE == 0) gxv = fmaf(w0, xs0[tt], bi);
                else           gxv = dot64(wv, &xstage[tt][0]) + p1s[g] + bi;
                gxb[knb][tt][g] = gxv;
            }
            __syncthreads();

            // last layer, reverse dir: only step 0 (p==L-1) feeds FC — stop.
            if (MODE == 2 && d == 1) return;
        }
    }

    // final flush of chunk NCH-1
    if (MODE <= 1) {
        const int base_prev = (NCH - 1) * TCH;
        if (tid < 512) {
            #pragma unroll
            for (int rr = 0; rr < 4; ++rr) {
                int idx = tid + rr * 512;
                int row = idx >> 5, col = idx & 31;
                u32 v = ((const u32*)loutb)[idx];
                ((u32*)(lout + ((size_t)bc * LSEQ + prow(base_prev + row)) * 128 + d * HID))[col] = v;
            }
        }
    }
}

// ---------------------------------------------------------------------------
// FC, SINGLE block (lastb aliases d_out[0:16384] — stage to LDS first).
// ---------------------------------------------------------------------------
__global__ __launch_bounds__(1024) void fc_single(
    const float* __restrict__ fcw,
    const float* __restrict__ fcb,
    float* __restrict__ out)           // == lastb
{
    __shared__ float ls[128 * 128];    // 64 KiB
    for (int i = threadIdx.x; i < 128 * 128; i += 1024) ls[i] = out[i];
    __syncthreads();
    for (int idx = threadIdx.x; idx < 128 * NCLS; idx += 1024) {
        const int b = idx / NCLS;
        const int c = idx % NCLS;
        const float4* w4 = (const float4*)(fcw + (size_t)c * 128);
        const float4* l4 = (const float4*)(ls + b * 128);
        float acc = fcb[c];
        #pragma unroll
        for (int i = 0; i < 32; ++i) {
            float4 w = w4[i], l = l4[i];
            acc += w.x*l.x + w.y*l.y + w.z*l.z + w.w*l.w;
        }
        out[idx] = acc;
    }
}

// ---------------------------------------------------------------------------
// Workspace: two bf16 ping-pong activation buffers (lastb lives in d_out).
// r8/r9: Bc=128 selected => ws_size >= 256 MiB. Ladder kept for safety.
// ---------------------------------------------------------------------------
extern "C" void kernel_launch(void* const* d_in, const int* in_sizes, int n_in,
                              void* d_out, int out_size, void* d_ws, size_t ws_size,
                              hipStream_t stream)
{
    if (n_in < 8) return;
    const float* x    = (const float*)d_in[0];   // [128][1][4096]
    const float* wih0 = (const float*)d_in[1];   // [2][192][1]
    const float* wih  = (const float*)d_in[2];   // [3][2][192][128]
    const float* whh  = (const float*)d_in[3];   // [4][2][192][64]
    const float* bih  = (const float*)d_in[4];   // [4][2][192]
    const float* bhh  = (const float*)d_in[5];   // [4][2][192]
    const float* fcw  = (const float*)d_in[6];   // [230][128]
    const float* fcb  = (const float*)d_in[7];   // [230]
    float* out   = (float*)d_out;
    float* lastb = out;                          // first 16384 floats of d_out

    const size_t seqb = (size_t)LSEQ * 128 * 2;  // 1 MiB per batch elem (bf16)
    int Bc = 0;
    {
        const int cand[] = {128, 96, 64, 48, 32, 24, 16, 12, 8, 4, 2, 1};
        for (int i = 0; i < 12; ++i)
            if (2ull * cand[i] * seqb <= ws_size) { Bc = cand[i]; break; }
    }
    if (Bc == 0) return;

    u16* bufA = (u16*)d_ws;
    u16* bufB = bufA + (size_t)Bc * LSEQ * 128;

    for (int bb = 0; bb < 128; ) {
        const int cur = (Bc < 128 - bb) ? Bc : (128 - bb);
        const float* xc = x + (size_t)bb * LSEQ;
        rec_cb<0><<<2*cur, 576, 0, stream>>>(xc,   wih0,        bih,        whh,          bhh,        bufA, nullptr, bb);
        rec_cb<1><<<2*cur, 576, 0, stream>>>(bufA, wih,         bih + 384,  whh + 24576,  bhh + 384,  bufB, nullptr, bb);
        rec_cb<1><<<2*cur, 576, 0, stream>>>(bufB, wih + 49152, bih + 768,  whh + 49152,  bhh + 768,  bufA, nullptr, bb);
        rec_cb<2><<<2*cur, 576, 0, stream>>>(bufA, wih + 98304, bih + 1152, whh + 73728,  bhh + 1152, nullptr, lastb, bb);
        bb += cur;
    }
    fc_single<<<1, 1024, 0, stream>>>(fcw, fcb, out);
}

// Round 12
// 8682.696 us; speedup vs baseline: 1.9117x; 1.9117x over previous
//
#include <hip/hip_runtime.h>
#include <cstdint>
#include <cstddef>

#define HID   64
#define G3    192
#define LSEQ  4096
#define NCLS  230
#define TCH   64              // steps per chunk
#define NCH   (LSEQ / TCH)    // 64 chunks

using u16 = unsigned short;
using u32 = unsigned int;
typedef _Float16 h2 __attribute__((ext_vector_type(2)));

__device__ __forceinline__ float bf2f(u16 u) { return __uint_as_float(((u32)u) << 16); }
__device__ __forceinline__ u16 f2bf(float f) {
    u32 x = __float_as_uint(f);
    x += 0x7fffu + ((x >> 16) & 1u);
    return (u16)(x >> 16);
}
// v_dot2_f32_f16: 2 f16 MACs, f32 accumulate
__device__ __forceinline__ float fdot2(h2 a, h2 b, float c) {
#if __has_builtin(__builtin_amdgcn_fdot2)
    return __builtin_amdgcn_fdot2(a, b, c, false);
#else
    return c + (float)a.x * (float)b.x + (float)a.y * (float)b.y;
#endif
}
// 2 packed bf16 -> 2 packed f16 (exact: bf16 mantissa 8b < f16 10b; |x|<=~8 in range)
__device__ __forceinline__ u32 bfpair_to_h2(u32 w) {
    _Float16 a = (_Float16)bf2f((u16)w);
    _Float16 b = (_Float16)bf2f((u16)(w >> 16));
    return (u32)__builtin_bit_cast(u16, a) | ((u32)__builtin_bit_cast(u16, b) << 16);
}

// ---------------------------------------------------------------------------
// Single-wave-scan GRU layer (r12). One block per (batch, dir), 448 threads:
//   wave 0  (tid 0-63):   THE SCAN. Lane j owns gate rows r_j, z_j, n_j with
//                         packed-f16 whh in VGPRs (3x32 half2 — resident).
//                         Per step: 96 fdot2 + 3 LDS gx reads + gates + one
//                         128B LDS h round-trip. ZERO barriers per step.
//   waves 1-6 (tid 64-447, pid=tid-64): producers — build gxb for chunk k+1
//                         (fdot2, 64-half2 wi rows), stage x (bf16->f16),
//                         flush lout chunk k-1. Sync with scan ONLY at chunk
//                         boundaries: 1 barrier per 64 steps.
// Rationale: r8/r9/r11 measured per-step cost pinned at ~1700-2800cy by
// cross-wave barriers; this removes them from the steady-state entirely.
// MODE 0: layer 0 (scalar f32 x); 1: middle; 2: last (writes lastb only).
// ---------------------------------------------------------------------------
template<int MODE>
__global__ __launch_bounds__(448, 1) void rec_sw(
    const void* __restrict__ xin,   // MODE0: [Bc][L] f32; else [Bc][L][128] bf16
    const float* __restrict__ wih,  // MODE0: [2][192]; else [2][192][128] f32
    const float* __restrict__ bih,  // [2][192] f32 (this layer)
    const float* __restrict__ whh,  // [2][192][64] f32 (this layer)
    const float* __restrict__ bhh,  // [2][192] f32 (this layer)
    u16* __restrict__ lout,         // [Bc][L][128] bf16 (MODE<=1)
    float* __restrict__ lastb,      // [B][128] f32 (MODE==2; aliases d_out)
    int bbase)
{
    const int bc  = blockIdx.x >> 1;
    const int d   = blockIdx.x & 1;
    const int tid = threadIdx.x;

    __shared__ float      gxb[2][TCH][G3];                  // 96 KiB
    __shared__ __align__(16) _Float16 xstage[2][TCH][128];  // 32 KiB (MODE>=1)
    __shared__ __align__(16) u16      loutb[2][TCH][HID];   //  8 KiB x2 = 16 KiB
    __shared__ __align__(16) _Float16 hb16[HID];            // 128 B
    __shared__ float      xs0[2][TCH];                      // 512 B (MODE0)

    const u16*   xb = (const u16*)xin + (size_t)bc * LSEQ * 128;
    const float* xp = (const float*)xin + (size_t)bc * LSEQ;
    auto prow = [&](int s) -> int { return d ? (LSEQ - 1 - s) : s; };

    const int kmax = (MODE == 2 && d == 1) ? 1 : NCH;

    // ---------------- per-role setup ----------------
    // scan wave registers
    h2 wr2[32], wz2[32], wn2[32], hp[32];
    float bhr = 0.f, bhz = 0.f, bhn = 0.f, hj = 0.f;
    // producer registers
    h2 wi2[64];
    float w0 = 0.f, bi = 0.f;
    int g = 0, tb = 0, pid = -1;

    if (tid < 64) {
        const int j = tid;
        auto loadrow = [&](const float* rowp, h2* dst) {
            const float4* p4 = (const float4*)rowp;
            #pragma unroll
            for (int i = 0; i < 16; ++i) {
                float4 v = p4[i];
                h2 a, b;
                a.x = (_Float16)v.x; a.y = (_Float16)v.y;
                b.x = (_Float16)v.z; b.y = (_Float16)v.w;
                dst[2*i] = a; dst[2*i+1] = b;
            }
        };
        loadrow(whh + (size_t)(d * G3 +       j) * HID, wr2);
        loadrow(whh + (size_t)(d * G3 +  64 + j) * HID, wz2);
        loadrow(whh + (size_t)(d * G3 + 128 + j) * HID, wn2);
        bhr = bhh[d * G3 + j];
        bhz = bhh[d * G3 + 64 + j];
        bhn = bhh[d * G3 + 128 + j];
        #pragma unroll
        for (int i = 0; i < 32; ++i) { h2 z0; z0.x = (_Float16)0.f; z0.y = (_Float16)0.f; hp[i] = z0; }
    } else {
        pid = tid - 64;              // 0..383
        g   = pid % G3;
        tb  = (pid / G3) * 32;       // 0 or 32
        bi  = bih[d * G3 + g];
        if (MODE == 0) {
            w0 = wih[d * G3 + g];
        } else {
            const float4* p4 = (const float4*)(wih + (size_t)(d * G3 + g) * 128);
            #pragma unroll
            for (int i = 0; i < 32; ++i) {
                float4 v = p4[i];
                h2 a, b;
                a.x = (_Float16)v.x; a.y = (_Float16)v.y;
                b.x = (_Float16)v.z; b.y = (_Float16)v.w;
                wi2[2*i] = a; wi2[2*i+1] = b;
            }
        }
    }

    // staging helper: chunk c -> xstage[c&1] / xs0[c&1] (stagers: pid<128 / pid<64)
    auto stage_chunk = [&](int c) {
        if (MODE == 0) {
            if (pid >= 0 && pid < TCH) xs0[c & 1][pid] = xp[prow(c * TCH + pid)];
        } else if (pid >= 0 && pid < 128) {
            const int base = c * TCH;
            #pragma unroll
            for (int it = 0; it < 8; ++it) {
                int idx = it * 128 + pid;        // 16B units over [64][128] f16
                int row = idx >> 4, seg = idx & 15;
                uint4 v = *(const uint4*)(xb + (size_t)prow(base + row) * 128 + seg * 8);
                uint4 o;
                o.x = bfpair_to_h2(v.x); o.y = bfpair_to_h2(v.y);
                o.z = bfpair_to_h2(v.z); o.w = bfpair_to_h2(v.w);
                *(uint4*)&xstage[c & 1][row][seg * 8] = o;
            }
        }
    };
    // producer helper: build gxb[c&1] for chunk c from xstage[c&1]
    auto produce_chunk = [&](int c) {
        const int nb = c & 1;
        if (MODE == 0) {
            for (int tt = tb; tt < tb + 32; ++tt)
                gxb[nb][tt][g] = fmaf(w0, xs0[nb][tt], bi);
        } else {
            for (int tt = tb; tt < tb + 32; ++tt) {
                const h2* xr = (const h2*)&xstage[nb][tt][0];
                float a0 = 0.f, a1 = 0.f;
                #pragma unroll
                for (int i = 0; i < 64; i += 2) {
                    a0 = fdot2(wi2[i],     xr[i],     a0);
                    a1 = fdot2(wi2[i + 1], xr[i + 1], a1);
                }
                gxb[nb][tt][g] = a0 + a1 + bi;
            }
        }
    };

    // ---------------- prologue ----------------
    if (tid >= 64) stage_chunk(0);
    __syncthreads();
    if (tid >= 64) {
        produce_chunk(0);
        if (kmax > 1) stage_chunk(1);
    }
    __syncthreads();

    // ---------------- main chunk loop ----------------
    for (int k = 0; k < kmax; ++k) {
        if (tid < 64) {
            // ================= THE SCAN (one wave, no barriers) =================
            __builtin_amdgcn_s_setprio(1);
            const int j  = tid;
            const int kb = k & 1;
            for (int tt = 0; tt < TCH; ++tt) {
                const float* gxrow = &gxb[kb][tt][0];
                const float gxr = gxrow[j];
                const float gxz = gxrow[64 + j];
                const float gxn = gxrow[128 + j];
                float ar = 0.f, br = 0.f, az = 0.f, bz = 0.f, an = 0.f, bn = 0.f;
                #pragma unroll
                for (int i = 0; i < 32; i += 2) {
                    ar = fdot2(wr2[i],   hp[i],   ar);
                    br = fdot2(wr2[i+1], hp[i+1], br);
                    az = fdot2(wz2[i],   hp[i],   az);
                    bz = fdot2(wz2[i+1], hp[i+1], bz);
                    an = fdot2(wn2[i],   hp[i],   an);
                    bn = fdot2(wn2[i+1], hp[i+1], bn);
                }
                const float ghr = ar + br + bhr;
                const float ghz = az + bz + bhz;
                const float ghn = an + bn + bhn;
                const float r = 1.f / (1.f + __expf(-(gxr + ghr)));
                const float z = 1.f / (1.f + __expf(-(gxz + ghz)));
                float y = fmaf(r, ghn, gxn);
                y = fminf(fmaxf(y, -15.f), 15.f);
                const float e = __expf(-2.f * y);
                const float n = (1.f - e) / (1.f + e);       // tanh(y)
                hj = fmaf(z, hj - n, n);                     // (1-z)*n + z*h
                hb16[j] = (_Float16)hj;
                if (MODE <= 1) loutb[kb][tt][j] = f2bf(hj);
                else {
                    if ((d == 0 && k == NCH - 1 && tt == TCH - 1) ||
                        (d == 1 && k == 0 && tt == 0))
                        lastb[(size_t)(bbase + bc) * 128 + d * HID + j] = hj;
                }
                // broadcast-read h back as packed f16 (same wave: lgkmcnt only)
                const uint4* hb4 = (const uint4*)hb16;
                #pragma unroll
                for (int i = 0; i < 8; ++i) {
                    uint4 v = hb4[i];
                    hp[4*i+0] = __builtin_bit_cast(h2, v.x);
                    hp[4*i+1] = __builtin_bit_cast(h2, v.y);
                    hp[4*i+2] = __builtin_bit_cast(h2, v.z);
                    hp[4*i+3] = __builtin_bit_cast(h2, v.w);
                }
            }
            __builtin_amdgcn_s_setprio(0);
        } else {
            // ================= producers / stagers / flusher =================
            if (k + 1 < kmax) produce_chunk(k + 1);
            if (k + 2 < kmax) stage_chunk(k + 2);
            if (MODE <= 1 && k > 0 && pid >= 320) {
                const int lane = pid - 320;
                const int base = (k - 1) * TCH;
                const int fb = (k - 1) & 1;
                for (int tt = 0; tt < TCH; ++tt)
                    lout[((size_t)bc * LSEQ + prow(base + tt)) * 128 + d * HID + lane] =
                        loutb[fb][tt][lane];
            }
        }
        __syncthreads();
    }

    // final flush (chunk kmax-1)
    if (MODE <= 1 && pid >= 320) {
        const int lane = pid - 320;
        const int base = (kmax - 1) * TCH;
        const int fb = (kmax - 1) & 1;
        for (int tt = 0; tt < TCH; ++tt)
            lout[((size_t)bc * LSEQ + prow(base + tt)) * 128 + d * HID + lane] =
                loutb[fb][tt][lane];
    }
}

// ---------------------------------------------------------------------------
// FC, SINGLE block (lastb aliases d_out[0:16384] — stage to LDS first).
// ---------------------------------------------------------------------------
__global__ __launch_bounds__(1024) void fc_single(
    const float* __restrict__ fcw,
    const float* __restrict__ fcb,
    float* __restrict__ out)           // == lastb
{
    __shared__ float ls[128 * 128];    // 64 KiB
    for (int i = threadIdx.x; i < 128 * 128; i += 1024) ls[i] = out[i];
    __syncthreads();
    for (int idx = threadIdx.x; idx < 128 * NCLS; idx += 1024) {
        const int b = idx / NCLS;
        const int c = idx % NCLS;
        const float4* w4 = (const float4*)(fcw + (size_t)c * 128);
        const float4* l4 = (const float4*)(ls + b * 128);
        float acc = fcb[c];
        #pragma unroll
        for (int i = 0; i < 32; ++i) {
            float4 w = w4[i], l = l4[i];
            acc += w.x*l.x + w.y*l.y + w.z*l.z + w.w*l.w;
        }
        out[idx] = acc;
    }
}

// ---------------------------------------------------------------------------
// Workspace: two bf16 ping-pong activation buffers (lastb lives in d_out).
// Measured (r7/r8): ws_size = 256 MiB exactly -> Bc=128, single pass.
// ---------------------------------------------------------------------------
extern "C" void kernel_launch(void* const* d_in, const int* in_sizes, int n_in,
                              void* d_out, int out_size, void* d_ws, size_t ws_size,
                              hipStream_t stream)
{
    if (n_in < 8) return;
    const float* x    = (const float*)d_in[0];   // [128][1][4096]
    const float* wih0 = (const float*)d_in[1];   // [2][192][1]
    const float* wih  = (const float*)d_in[2];   // [3][2][192][128]
    const float* whh  = (const float*)d_in[3];   // [4][2][192][64]
    const float* bih  = (const float*)d_in[4];   // [4][2][192]
    const float* bhh  = (const float*)d_in[5];   // [4][2][192]
    const float* fcw  = (const float*)d_in[6];   // [230][128]
    const float* fcb  = (const float*)d_in[7];   // [230]
    float* out   = (float*)d_out;
    float* lastb = out;                          // first 16384 floats of d_out

    const size_t seqb = (size_t)LSEQ * 128 * 2;  // 1 MiB per batch elem (bf16)
    int Bc = 0;
    {
        const int cand[] = {128, 96, 64, 48, 32, 24, 16, 12, 8, 4, 2, 1};
        for (int i = 0; i < 12; ++i)
            if (2ull * cand[i] * seqb <= ws_size) { Bc = cand[i]; break; }
    }
    if (Bc == 0) return;

    u16* bufA = (u16*)d_ws;
    u16* bufB = bufA + (size_t)Bc * LSEQ * 128;

    for (int bb = 0; bb < 128; ) {
        const int cur = (Bc < 128 - bb) ? Bc : (128 - bb);
        const float* xc = x + (size_t)bb * LSEQ;
        rec_sw<0><<<2*cur, 448, 0, stream>>>(xc,   wih0,        bih,        whh,          bhh,        bufA, nullptr, bb);
        rec_sw<1><<<2*cur, 448, 0, stream>>>(bufA, wih,         bih + 384,  whh + 24576,  bhh + 384,  bufB, nullptr, bb);
        rec_sw<1><<<2*cur, 448, 0, stream>>>(bufB, wih + 49152, bih + 768,  whh + 49152,  bhh + 768,  bufA, nullptr, bb);
        rec_sw<2><<<2*cur, 448, 0, stream>>>(bufA, wih + 98304, bih + 1152, whh + 73728,  bhh + 1152, nullptr, lastb, bb);
        bb += cur;
    }
    fc_single<<<1, 1024, 0, stream>>>(fcw, fcb, out);
}

// Round 14
// 8605.675 us; speedup vs baseline: 1.9288x; 1.0090x over previous
//
#include <hip/hip_runtime.h>
#include <cstdint>
#include <cstddef>

#define HID   64
#define G3    192
#define LSEQ  4096
#define NCLS  230
#define TCH   64              // steps per chunk
#define NCH   (LSEQ / TCH)    // 64 chunks

using u16 = unsigned short;
using u32 = unsigned int;
typedef _Float16 h2 __attribute__((ext_vector_type(2)));

__device__ __forceinline__ float bf2f(u16 u) { return __uint_as_float(((u32)u) << 16); }
__device__ __forceinline__ u16 f2bf(float f) {
    u32 x = __float_as_uint(f);
    x += 0x7fffu + ((x >> 16) & 1u);
    return (u16)(x >> 16);
}
__device__ __forceinline__ h2 bch2(u32 v) { return __builtin_bit_cast(h2, v); }
// v_dot2_f32_f16: 2 f16 MACs, f32 accumulate
__device__ __forceinline__ float fdot2(h2 a, h2 b, float c) {
#if __has_builtin(__builtin_amdgcn_fdot2)
    return __builtin_amdgcn_fdot2(a, b, c, false);
#else
    return c + (float)a.x * (float)b.x + (float)a.y * (float)b.y;
#endif
}
// 2 packed bf16 -> 2 packed f16 (exact in our value range)
__device__ __forceinline__ u32 bfpair_to_h2(u32 w) {
    _Float16 a = (_Float16)bf2f((u16)w);
    _Float16 b = (_Float16)bf2f((u16)(w >> 16));
    return (u32)__builtin_bit_cast(u16, a) | ((u32)__builtin_bit_cast(u16, b) << 16);
}

// ---------------------------------------------------------------------------
// Single-wave-scan GRU layer (r13 = lean r12). One block per (batch, dir),
// 448 threads:
//   wave 0 (tid 0-63): THE SCAN — zero barriers per step. Lane j owns gate
//     rows r_j, z_j, n_j (packed-f16 whh in 96 VGPRs). Per step: read h (8x
//     b128 broadcast, consumed DIRECTLY — no persistent hp array), 96 fdot2,
//     gates in-lane, early hb16 write, gx prefetch for t+1.
//   waves 1-6: producers (gxb for chunk k+1, b128 LDS reads), x stagers
//     (bf16->f16), lout flusher. Sync with scan only at chunk boundaries.
// r12 measured 1360 cy/step vs ~650 model; this round removes the hp-array
// round trip, prefetches gx, and vectorizes producer LDS reads.
// MODE 0: layer 0 (scalar f32 x); 1: middle; 2: last (writes lastb only).
// ---------------------------------------------------------------------------
template<int MODE>
__global__ __launch_bounds__(448, 1) void rec_sw(
    const void* __restrict__ xin,   // MODE0: [Bc][L] f32; else [Bc][L][128] bf16
    const float* __restrict__ wih,  // MODE0: [2][192]; else [2][192][128] f32
    const float* __restrict__ bih,  // [2][192] f32 (this layer)
    const float* __restrict__ whh,  // [2][192][64] f32 (this layer)
    const float* __restrict__ bhh,  // [2][192] f32 (this layer)
    u16* __restrict__ lout,         // [Bc][L][128] bf16 (MODE<=1)
    float* __restrict__ lastb,      // [B][128] f32 (MODE==2; aliases d_out)
    int bbase)
{
    const int bc  = blockIdx.x >> 1;
    const int d   = blockIdx.x & 1;
    const int tid = threadIdx.x;

    __shared__ float      gxb[2][TCH][G3];                  // 96 KiB
    __shared__ __align__(16) _Float16 xstage[2][TCH][128];  // 32 KiB (MODE>=1)
    __shared__ __align__(16) u16      loutb[2][TCH][HID];   // 16 KiB
    __shared__ __align__(16) _Float16 hb16[HID];            // 128 B
    __shared__ float      xs0[2][TCH];                      // 512 B (MODE0)

    const u16*   xb = (const u16*)xin + (size_t)bc * LSEQ * 128;
    const float* xp = (const float*)xin + (size_t)bc * LSEQ;
    auto prow = [&](int s) -> int { return d ? (LSEQ - 1 - s) : s; };

    const int kmax = (MODE == 2 && d == 1) ? 1 : NCH;

    // ---------------- per-role setup ----------------
    h2 wr2[32], wz2[32], wn2[32];                  // scan weights (f16 pairs)
    float bhr = 0.f, bhz = 0.f, bhn = 0.f, hj = 0.f;
    h2 wi2[64];                                     // producer weights
    float w0 = 0.f, bi = 0.f;
    int g = 0, tb = 0, pid = -1;

    if (tid < 64) {
        const int j = tid;
        auto loadrow = [&](const float* rowp, h2* dst) {
            const float4* p4 = (const float4*)rowp;
            #pragma unroll
            for (int i = 0; i < 16; ++i) {
                float4 v = p4[i];
                h2 a, b;
                a.x = (_Float16)v.x; a.y = (_Float16)v.y;
                b.x = (_Float16)v.z; b.y = (_Float16)v.w;
                dst[2*i] = a; dst[2*i+1] = b;
            }
        };
        loadrow(whh + (size_t)(d * G3 +       j) * HID, wr2);
        loadrow(whh + (size_t)(d * G3 +  64 + j) * HID, wz2);
        loadrow(whh + (size_t)(d * G3 + 128 + j) * HID, wn2);
        bhr = bhh[d * G3 + j];
        bhz = bhh[d * G3 + 64 + j];
        bhn = bhh[d * G3 + 128 + j];
        hb16[j] = (_Float16)0.f;                    // step 0 reads hb16!
    } else {
        pid = tid - 64;              // 0..383
        g   = pid % G3;
        tb  = (pid / G3) * 32;       // 0 or 32
        bi  = bih[d * G3 + g];
        if (MODE == 0) {
            w0 = wih[d * G3 + g];
        } else {
            const float4* p4 = (const float4*)(wih + (size_t)(d * G3 + g) * 128);
            #pragma unroll
            for (int i = 0; i < 32; ++i) {
                float4 v = p4[i];
                h2 a, b;
                a.x = (_Float16)v.x; a.y = (_Float16)v.y;
                b.x = (_Float16)v.z; b.y = (_Float16)v.w;
                wi2[2*i] = a; wi2[2*i+1] = b;
            }
        }
    }

    // staging helper: chunk c -> xstage[c&1] / xs0[c&1]
    auto stage_chunk = [&](int c) {
        if (MODE == 0) {
            if (pid >= 0 && pid < TCH) xs0[c & 1][pid] = xp[prow(c * TCH + pid)];
        } else if (pid >= 0 && pid < 128) {
            const int base = c * TCH;
            #pragma unroll
            for (int it = 0; it < 8; ++it) {
                int idx = it * 128 + pid;        // 16B units over [64][128] f16
                int row = idx >> 4, seg = idx & 15;
                uint4 v = *(const uint4*)(xb + (size_t)prow(base + row) * 128 + seg * 8);
                uint4 o;
                o.x = bfpair_to_h2(v.x); o.y = bfpair_to_h2(v.y);
                o.z = bfpair_to_h2(v.z); o.w = bfpair_to_h2(v.w);
                *(uint4*)&xstage[c & 1][row][seg * 8] = o;
            }
        }
    };
    // producer: build gxb[c&1] for chunk c (b128 LDS reads, broadcast rows)
    auto produce_chunk = [&](int c) {
        const int nb = c & 1;
        if (MODE == 0) {
            for (int tt = tb; tt < tb + 32; ++tt)
                gxb[nb][tt][g] = fmaf(w0, xs0[nb][tt], bi);
        } else {
            for (int tt = tb; tt < tb + 32; ++tt) {
                const uint4* xr4 = (const uint4*)&xstage[nb][tt][0];
                float a0 = 0.f, a1 = 0.f;
                #pragma unroll
                for (int i = 0; i < 16; ++i) {
                    uint4 q = xr4[i];
                    a0 = fdot2(wi2[4*i+0], bch2(q.x), a0);
                    a1 = fdot2(wi2[4*i+1], bch2(q.y), a1);
                    a0 = fdot2(wi2[4*i+2], bch2(q.z), a0);
                    a1 = fdot2(wi2[4*i+3], bch2(q.w), a1);
                }
                gxb[nb][tt][g] = a0 + a1 + bi;
            }
        }
    };

    // ---------------- prologue ----------------
    if (tid >= 64) stage_chunk(0);
    __syncthreads();
    if (tid >= 64) {
        produce_chunk(0);
        if (kmax > 1) stage_chunk(1);
    }
    __syncthreads();

    // ---------------- main chunk loop ----------------
    for (int k = 0; k < kmax; ++k) {
        if (tid < 64) {
            // ============ THE SCAN (one wave, no barriers) ============
            __builtin_amdgcn_s_setprio(1);
            const int j  = tid;
            const int kb = k & 1;
            const uint4* hb4 = (const uint4*)hb16;
            // preload gx for tt=0 of this chunk
            float gxr = gxb[kb][0][j];
            float gxz = gxb[kb][0][64 + j];
            float gxn = gxb[kb][0][128 + j];
            for (int tt = 0; tt < TCH; ++tt) {
                // phase 1: h[0:32] — consume loads directly, no hp array
                float ar = 0.f, az = 0.f, an = 0.f;
                float br = 0.f, bz = 0.f, bn = 0.f;
                {
                    uint4 q0 = hb4[0], q1 = hb4[1], q2 = hb4[2], q3 = hb4[3];
                    #define DOTQ(Q, B, XR, XZ, XN)                          \
                        XR = fdot2(wr2[B+0], bch2(Q.x), XR);                \
                        XZ = fdot2(wz2[B+0], bch2(Q.x), XZ);                \
                        XN = fdot2(wn2[B+0], bch2(Q.x), XN);                \
                        XR = fdot2(wr2[B+1], bch2(Q.y), XR);                \
                        XZ = fdot2(wz2[B+1], bch2(Q.y), XZ);                \
                        XN = fdot2(wn2[B+1], bch2(Q.y), XN);                \
                        XR = fdot2(wr2[B+2], bch2(Q.z), XR);                \
                        XZ = fdot2(wz2[B+2], bch2(Q.z), XZ);                \
                        XN = fdot2(wn2[B+2], bch2(Q.z), XN);                \
                        XR = fdot2(wr2[B+3], bch2(Q.w), XR);                \
                        XZ = fdot2(wz2[B+3], bch2(Q.w), XZ);                \
                        XN = fdot2(wn2[B+3], bch2(Q.w), XN);
                    DOTQ(q0,  0, ar, az, an)
                    DOTQ(q1,  4, br, bz, bn)
                    DOTQ(q2,  8, ar, az, an)
                    DOTQ(q3, 12, br, bz, bn)
                }
                // phase 2: h[32:64]
                {
                    uint4 q4 = hb4[4], q5 = hb4[5], q6 = hb4[6], q7 = hb4[7];
                    DOTQ(q4, 16, ar, az, an)
                    DOTQ(q5, 20, br, bz, bn)
                    DOTQ(q6, 24, ar, az, an)
                    DOTQ(q7, 28, br, bz, bn)
                    #undef DOTQ
                }
                const float ghr = (ar + br) + bhr;
                const float ghz = (az + bz) + bhz;
                const float ghn = (an + bn) + bhn;
                const float r = 1.f / (1.f + __expf(-(gxr + ghr)));
                const float z = 1.f / (1.f + __expf(-(gxz + ghz)));
                float y = fmaf(r, ghn, gxn);
                y = fminf(fmaxf(y, -15.f), 15.f);
                const float e = __expf(-2.f * y);
                const float n = (1.f - e) / (1.f + e);       // tanh(y)
                hj = fmaf(z, hj - n, n);                     // (1-z)*n + z*h
                hb16[j] = (_Float16)hj;                      // EARLY write
                // prefetch next step's gx while the write retires
                if (tt + 1 < TCH) {
                    gxr = gxb[kb][tt + 1][j];
                    gxz = gxb[kb][tt + 1][64 + j];
                    gxn = gxb[kb][tt + 1][128 + j];
                }
                if (MODE <= 1) {
                    loutb[kb][tt][j] = f2bf(hj);
                } else if (d == 1 && tt == 0) {              // k==0 only (kmax=1)
                    lastb[(size_t)(bbase + bc) * 128 + HID + j] = hj;
                }
            }
            __builtin_amdgcn_s_setprio(0);
        } else {
            // ============ producers / stagers / flusher ============
            if (k + 1 < kmax) produce_chunk(k + 1);
            if (k + 2 < kmax) stage_chunk(k + 2);
            if (MODE <= 1 && k > 0 && pid >= 320) {
                const int lane = pid - 320;
                const int base = (k - 1) * TCH;
                const int fb = (k - 1) & 1;
                for (int tt = 0; tt < TCH; ++tt)
                    lout[((size_t)bc * LSEQ + prow(base + tt)) * 128 + d * HID + lane] =
                        loutb[fb][tt][lane];
            }
        }
        __syncthreads();
    }

    // MODE2 fwd: final h is the FC input
    if (MODE == 2 && d == 0 && tid < 64)
        lastb[(size_t)(bbase + bc) * 128 + tid] = hj;

    // final flush (chunk kmax-1)
    if (MODE <= 1 && pid >= 320) {
        const int lane = pid - 320;
        const int base = (kmax - 1) * TCH;
        const int fb = (kmax - 1) & 1;
        for (int tt = 0; tt < TCH; ++tt)
            lout[((size_t)bc * LSEQ + prow(base + tt)) * 128 + d * HID + lane] =
                loutb[fb][tt][lane];
    }
}

// ---------------------------------------------------------------------------
// FC, SINGLE block (lastb aliases d_out[0:16384] — stage to LDS first).
// ---------------------------------------------------------------------------
__global__ __launch_bounds__(1024) void fc_single(
    const float* __restrict__ fcw,
    const float* __restrict__ fcb,
    float* __restrict__ out)           // == lastb
{
    __shared__ float ls[128 * 128];    // 64 KiB
    for (int i = threadIdx.x; i < 128 * 128; i += 1024) ls[i] = out[i];
    __syncthreads();
    for (int idx = threadIdx.x; idx < 128 * NCLS; idx += 1024) {
        const int b = idx / NCLS;
        const int c = idx % NCLS;
        const float4* w4 = (const float4*)(fcw + (size_t)c * 128);
        const float4* l4 = (const float4*)(ls + b * 128);
        float acc = fcb[c];
        #pragma unroll
        for (int i = 0; i < 32; ++i) {
            float4 w = w4[i], l = l4[i];
            acc += w.x*l.x + w.y*l.y + w.z*l.z + w.w*l.w;
        }
        out[idx] = acc;
    }
}

// ---------------------------------------------------------------------------
// Workspace: two bf16 ping-pong activation buffers (lastb lives in d_out).
// Measured: ws_size = 256 MiB -> Bc=128, single pass.
// ---------------------------------------------------------------------------
extern "C" void kernel_launch(void* const* d_in, const int* in_sizes, int n_in,
                              void* d_out, int out_size, void* d_ws, size_t ws_size,
                              hipStream_t stream)
{
    if (n_in < 8) return;
    const float* x    = (const float*)d_in[0];   // [128][1][4096]
    const float* wih0 = (const float*)d_in[1];   // [2][192][1]
    const float* wih  = (const float*)d_in[2];   // [3][2][192][128]
    const float* whh  = (const float*)d_in[3];   // [4][2][192][64]
    const float* bih  = (const float*)d_in[4];   // [4][2][192]
    const float* bhh  = (const float*)d_in[5];   // [4][2][192]
    const float* fcw  = (const float*)d_in[6];   // [230][128]
    const float* fcb  = (const float*)d_in[7];   // [230]
    float* out   = (float*)d_out;
    float* lastb = out;                          // first 16384 floats of d_out

    const size_t seqb = (size_t)LSEQ * 128 * 2;  // 1 MiB per batch elem (bf16)
    int Bc = 0;
    {
        const int cand[] = {128, 96, 64, 48, 32, 24, 16, 12, 8, 4, 2, 1};
        for (int i = 0; i < 12; ++i)
            if (2ull * cand[i] * seqb <= ws_size) { Bc = cand[i]; break; }
    }
    if (Bc == 0) return;

    u16* bufA = (u16*)d_ws;
    u16* bufB = bufA + (size_t)Bc * LSEQ * 128;

    for (int bb = 0; bb < 128; ) {
        const int cur = (Bc < 128 - bb) ? Bc : (128 - bb);
        const float* xc = x + (size_t)bb * LSEQ;
        rec_sw<0><<<2*cur, 448, 0, stream>>>(xc,   wih0,        bih,        whh,          bhh,        bufA, nullptr, bb);
        rec_sw<1><<<2*cur, 448, 0, stream>>>(bufA, wih,         bih + 384,  whh + 24576,  bhh + 384,  bufB, nullptr, bb);
        rec_sw<1><<<2*cur, 448, 0, stream>>>(bufB, wih + 49152, bih + 768,  whh + 49152,  bhh + 768,  bufA, nullptr, bb);
        rec_sw<2><<<2*cur, 448, 0, stream>>>(bufA, wih + 98304, bih + 1152, whh + 73728,  bhh + 1152, nullptr, lastb, bb);
        bb += cur;
    }
    fc_single<<<1, 1024, 0, stream>>>(fcw, fcb, out);
}